// Round 1
// baseline (2065.010 us; speedup 1.0000x reference)
//
#include <hip/hip_runtime.h>
#include <math.h>

#define S_LEN 2048
#define B_SZ 2
#define DMODEL 1024
#define NH 16
#define DK 64
#define NEGV -1e9f

// ---------------------------------------------------------------------------
// Generic tiled fp32 GEMM + bias: C[M,N] = A[M,K] @ B[K,N] + bias[N]
// 64x64 tile, BK=16, 256 threads, 4x4 microtile per thread.
// ---------------------------------------------------------------------------
__global__ __launch_bounds__(256) void gemm_bias_k(
    const float* __restrict__ A, const float* __restrict__ B,
    const float* __restrict__ bias, float* __restrict__ C,
    int M, int N, int K)
{
    __shared__ float As[16][65];   // [k][row] +1 pad
    __shared__ float Bs[16][65];   // [k][col] +1 pad
    const int tid = threadIdx.x;
    const int tx = tid & 15, ty = tid >> 4;
    const int row0 = blockIdx.y * 64, col0 = blockIdx.x * 64;
    float acc[4][4] = {};

    for (int k0 = 0; k0 < K; k0 += 16) {
        __syncthreads();
#pragma unroll
        for (int t = 0; t < 4; ++t) {
            int idx = tid + t * 256;
            int c = idx & 15, r = idx >> 4;          // A tile: 64 rows x 16 k
            As[c][r] = A[(size_t)(row0 + r) * K + (k0 + c)];
            int rb = idx >> 6, cb = idx & 63;        // B tile: 16 k x 64 cols
            Bs[rb][cb] = B[(size_t)(k0 + rb) * N + (col0 + cb)];
        }
        __syncthreads();
#pragma unroll
        for (int kk = 0; kk < 16; ++kk) {
            float a[4], b[4];
#pragma unroll
            for (int i = 0; i < 4; ++i) a[i] = As[kk][ty * 4 + i];
#pragma unroll
            for (int j = 0; j < 4; ++j) b[j] = Bs[kk][tx * 4 + j];
#pragma unroll
            for (int i = 0; i < 4; ++i)
#pragma unroll
                for (int j = 0; j < 4; ++j)
                    acc[i][j] += a[i] * b[j];
        }
    }
#pragma unroll
    for (int i = 0; i < 4; ++i) {
        int row = row0 + ty * 4 + i;
#pragma unroll
        for (int j = 0; j < 4; ++j) {
            int col = col0 + tx * 4 + j;
            C[(size_t)row * N + col] = acc[i][j] + bias[col];
        }
    }
}

// ---------------------------------------------------------------------------
// Masked scores: attn[bh][q][k] = (Q_h[q] . K_h[k]) / 8, or NEG if masked.
// One block = 64 q x 64 k tile for one (b,h). Full d_k=64 staged in LDS.
// ---------------------------------------------------------------------------
__global__ __launch_bounds__(256) void scores_k(
    const float* __restrict__ Q, const float* __restrict__ K,
    const int* __restrict__ tok, float* __restrict__ attn)
{
    const int bh = blockIdx.z;               // 0..31
    const int b = bh >> 4, h = bh & 15;
    const int q0 = blockIdx.y * 64;
    const int k0 = blockIdx.x * 64;
    const int tid = threadIdx.x;
    const int tx = tid & 15, ty = tid >> 4;
    float* aout = attn + (size_t)bh * S_LEN * S_LEN;

    if (k0 > q0 + 63) {                      // fully causal-masked tile
#pragma unroll
        for (int i = 0; i < 4; ++i) {
            size_t qrow = (size_t)(q0 + ty * 4 + i) * S_LEN;
#pragma unroll
            for (int j = 0; j < 4; ++j)
                aout[qrow + k0 + tx * 4 + j] = NEGV;
        }
        return;
    }

    __shared__ float Qs[64][65];             // [kdim][qrow]
    __shared__ float Ks[64][65];             // [kdim][kcol]
#pragma unroll
    for (int t = 0; t < 16; ++t) {
        int idx = tid + t * 256;
        int c = idx & 63, r = idx >> 6;
        Qs[c][r] = Q[((size_t)(b * S_LEN + q0 + r)) * DMODEL + h * DK + c];
        Ks[c][r] = K[((size_t)(b * S_LEN + k0 + r)) * DMODEL + h * DK + c];
    }
    __syncthreads();

    float acc[4][4] = {};
#pragma unroll 16
    for (int kk = 0; kk < 64; ++kk) {
        float a[4], bb[4];
#pragma unroll
        for (int i = 0; i < 4; ++i) a[i] = Qs[kk][ty * 4 + i];
#pragma unroll
        for (int j = 0; j < 4; ++j) bb[j] = Ks[kk][tx * 4 + j];
#pragma unroll
        for (int i = 0; i < 4; ++i)
#pragma unroll
            for (int j = 0; j < 4; ++j)
                acc[i][j] += a[i] * bb[j];
    }

#pragma unroll
    for (int i = 0; i < 4; ++i) {
        int q = q0 + ty * 4 + i;
#pragma unroll
        for (int j = 0; j < 4; ++j) {
            int kc = k0 + tx * 4 + j;
            bool masked = (kc > q) || (tok[b * S_LEN + kc] == 0);
            aout[(size_t)q * S_LEN + kc] = masked ? NEGV : acc[i][j] * 0.125f;
        }
    }
}

// ---------------------------------------------------------------------------
// In-place row softmax over 2048 entries. One block (256 thr) per row.
// Finite NEG (-1e9) reproduces the reference's uniform-softmax behavior for
// fully-masked rows: max = -1e9 -> exp(0)=1 everywhere -> 1/2048 each.
// ---------------------------------------------------------------------------
__global__ __launch_bounds__(256) void softmax_k(float* __restrict__ attn)
{
    float* p = attn + (size_t)blockIdx.x * S_LEN;
    const int tid = threadIdx.x;
    __shared__ float red[256];

    float v[8];
    float m = -INFINITY;
#pragma unroll
    for (int j = 0; j < 8; ++j) { v[j] = p[tid + j * 256]; m = fmaxf(m, v[j]); }
    red[tid] = m;
    __syncthreads();
    for (int s = 128; s > 0; s >>= 1) {
        if (tid < s) red[tid] = fmaxf(red[tid], red[tid + s]);
        __syncthreads();
    }
    m = red[0];
    __syncthreads();

    float sum = 0.f;
#pragma unroll
    for (int j = 0; j < 8; ++j) { v[j] = __expf(v[j] - m); sum += v[j]; }
    red[tid] = sum;
    __syncthreads();
    for (int s = 128; s > 0; s >>= 1) {
        if (tid < s) red[tid] += red[tid + s];
        __syncthreads();
    }
    float inv = 1.0f / red[0];
#pragma unroll
    for (int j = 0; j < 8; ++j) p[tid + j * 256] = v[j] * inv;
}

// ---------------------------------------------------------------------------
// ctx[b, q, h*64+d] = sum_k attn[bh][q][k] * V[b, k, h*64+d]
// One block = 64 q-rows x full d_k=64 for one (b,h); BK=16 over S=2048.
// NOTE: k-loop runs over all 2048 keys (not truncated at the diagonal) so
// fully-masked rows (uniform attn) stay correct.
// ---------------------------------------------------------------------------
__global__ __launch_bounds__(256) void av_k(
    const float* __restrict__ attn, const float* __restrict__ V,
    float* __restrict__ ctx)
{
    const int bh = blockIdx.y;
    const int b = bh >> 4, h = bh & 15;
    const int q0 = blockIdx.x * 64;
    const int tid = threadIdx.x;
    const int tx = tid & 15, ty = tid >> 4;
    const float* A = attn + (size_t)bh * S_LEN * S_LEN;

    __shared__ float As[16][65];   // [k][qrow]
    __shared__ float Bs[16][65];   // [k][d]
    float acc[4][4] = {};

    for (int k0 = 0; k0 < S_LEN; k0 += 16) {
        __syncthreads();
#pragma unroll
        for (int t = 0; t < 4; ++t) {
            int idx = tid + t * 256;
            int c = idx & 15, r = idx >> 4;
            As[c][r] = A[(size_t)(q0 + r) * S_LEN + (k0 + c)];
            int rb = idx >> 6, cb = idx & 63;
            Bs[rb][cb] = V[((size_t)(b * S_LEN + k0 + rb)) * DMODEL + h * DK + cb];
        }
        __syncthreads();
#pragma unroll
        for (int kk = 0; kk < 16; ++kk) {
            float a[4], bb[4];
#pragma unroll
            for (int i = 0; i < 4; ++i) a[i] = As[kk][ty * 4 + i];
#pragma unroll
            for (int j = 0; j < 4; ++j) bb[j] = Bs[kk][tx * 4 + j];
#pragma unroll
            for (int i = 0; i < 4; ++i)
#pragma unroll
                for (int j = 0; j < 4; ++j)
                    acc[i][j] += a[i] * bb[j];
        }
    }
#pragma unroll
    for (int i = 0; i < 4; ++i) {
        size_t orow = ((size_t)(b * S_LEN + q0 + ty * 4 + i)) * DMODEL + h * DK;
#pragma unroll
        for (int j = 0; j < 4; ++j)
            ctx[orow + tx * 4 + j] = acc[i][j];
    }
}

extern "C" void kernel_launch(void* const* d_in, const int* in_sizes, int n_in,
                              void* d_out, int out_size, void* d_ws, size_t ws_size,
                              hipStream_t stream) {
    const float* x  = (const float*)d_in[0];
    const int*  tok = (const int*)d_in[1];
    const float* wq = (const float*)d_in[2];
    const float* bq = (const float*)d_in[3];
    const float* wk = (const float*)d_in[4];
    const float* bk = (const float*)d_in[5];
    const float* wv = (const float*)d_in[6];
    const float* bv = (const float*)d_in[7];
    const float* wo = (const float*)d_in[8];
    const float* bo = (const float*)d_in[9];

    float* out  = (float*)d_out;                              // [B,S,D]
    float* attn = out + (size_t)B_SZ * S_LEN * DMODEL;        // [B,H,S,S]

    const size_t NTOK = (size_t)B_SZ * S_LEN;                 // 4096
    float* Q   = (float*)d_ws;                                // 16 MB each
    float* Kp  = Q  + NTOK * DMODEL;
    float* Vp  = Kp + NTOK * DMODEL;
    float* ctx = Vp + NTOK * DMODEL;

    dim3 blk(256);
    dim3 g_gemm(DMODEL / 64, (int)(NTOK / 64));               // (16, 64)

    gemm_bias_k<<<g_gemm, blk, 0, stream>>>(x,   wq, bq, Q,  (int)NTOK, DMODEL, DMODEL);
    gemm_bias_k<<<g_gemm, blk, 0, stream>>>(x,   wk, bk, Kp, (int)NTOK, DMODEL, DMODEL);
    gemm_bias_k<<<g_gemm, blk, 0, stream>>>(x,   wv, bv, Vp, (int)NTOK, DMODEL, DMODEL);

    scores_k<<<dim3(S_LEN / 64, S_LEN / 64, B_SZ * NH), blk, 0, stream>>>(Q, Kp, tok, attn);
    softmax_k<<<dim3(B_SZ * NH * S_LEN), blk, 0, stream>>>(attn);
    av_k<<<dim3(S_LEN / 64, B_SZ * NH), blk, 0, stream>>>(attn, Vp, ctx);

    gemm_bias_k<<<g_gemm, blk, 0, stream>>>(ctx, wo, bo, out, (int)NTOK, DMODEL, DMODEL);
}

// Round 2
// 907.810 us; speedup vs baseline: 2.2747x; 2.2747x over previous
//
#include <hip/hip_runtime.h>
#include <hip/hip_bf16.h>
#include <math.h>

#define S_LEN 2048
#define B_SZ 2
#define DMODEL 1024
#define NH 16
#define DK 64
#define NEGV -1e9f

typedef __attribute__((ext_vector_type(8))) short bf16x8;
typedef __attribute__((ext_vector_type(4))) float f32x4;

__device__ inline short f2bf(float f) {
    __hip_bfloat16 h = __float2bfloat16(f);
    return __builtin_bit_cast(short, h);
}
__device__ inline float bf2f(short s) {
    unsigned int u = ((unsigned int)(unsigned short)s) << 16;
    return __builtin_bit_cast(float, u);
}
__device__ inline f32x4 mfma16(bf16x8 a, bf16x8 b, f32x4 c) {
    return __builtin_amdgcn_mfma_f32_16x16x32_bf16(a, b, c, 0, 0, 0);
}

// ---------------------------------------------------------------------------
// fp32 -> bf16 elementwise convert (x)
// ---------------------------------------------------------------------------
__global__ __launch_bounds__(256) void cvt_bf16(const float* __restrict__ in,
                                                short* __restrict__ out, int n4) {
    int i = blockIdx.x * 256 + threadIdx.x;
    if (i < n4) {
        float4 v = *(const float4*)&in[(size_t)i * 4];
        short4 o = { f2bf(v.x), f2bf(v.y), f2bf(v.z), f2bf(v.w) };
        *(short4*)&out[(size_t)i * 4] = o;
    }
}

// ---------------------------------------------------------------------------
// Weight transpose+convert: W fp32 [K=1024][N=1024] -> Wt bf16 [N][K]
// ---------------------------------------------------------------------------
__global__ __launch_bounds__(256) void wtrans(const float* __restrict__ W,
                                              short* __restrict__ Wt) {
    __shared__ __align__(16) short T[64][72];
    const int k0 = blockIdx.x * 64, n0 = blockIdx.y * 64;
    const int tid = threadIdx.x;
#pragma unroll
    for (int i = 0; i < 4; ++i) {
        int idx = tid + i * 256;          // 64 k-rows x 16 float4
        int kr = idx >> 4, n4 = idx & 15;
        float4 v = *(const float4*)&W[(size_t)(k0 + kr) * DMODEL + n0 + n4 * 4];
        short4 o = { f2bf(v.x), f2bf(v.y), f2bf(v.z), f2bf(v.w) };
        *(short4*)&T[kr][n4 * 4] = o;
    }
    __syncthreads();
#pragma unroll
    for (int i = 0; i < 2; ++i) {
        int idx = tid + i * 256;          // 64 n-rows x 8 chunks(8 shorts)
        int n = idx >> 3, c8 = idx & 7;
        short v[8];
#pragma unroll
        for (int j = 0; j < 8; ++j) v[j] = T[c8 * 8 + j][n];
        *(int4*)&Wt[(size_t)(n0 + n) * DMODEL + k0 + c8 * 8] = *(int4*)v;
    }
}

// ---------------------------------------------------------------------------
// V transpose (per head): Vb bf16 [b][s][1024] -> Vt bf16 [bh][64 d][2048 s]
// ---------------------------------------------------------------------------
__global__ __launch_bounds__(256) void vtrans(const short* __restrict__ Vb,
                                              short* __restrict__ Vt) {
    __shared__ __align__(16) short T[64][72];
    const int bh = blockIdx.y, b = bh >> 4, h = bh & 15;
    const int s0 = blockIdx.x * 64;
    const int tid = threadIdx.x;
#pragma unroll
    for (int i = 0; i < 2; ++i) {
        int idx = tid + i * 256;          // 64 token-rows x 8 chunks
        int r = idx >> 3, c8 = idx & 7;
        *(int4*)&T[r][c8 * 8] =
            *(const int4*)&Vb[((size_t)(b * S_LEN + s0 + r)) * DMODEL + h * DK + c8 * 8];
    }
    __syncthreads();
#pragma unroll
    for (int i = 0; i < 2; ++i) {
        int idx = tid + i * 256;          // 64 d-rows x 8 chunks
        int d = idx >> 3, c8 = idx & 7;
        short v[8];
#pragma unroll
        for (int j = 0; j < 8; ++j) v[j] = T[c8 * 8 + j][d];
        *(int4*)&Vt[((size_t)(bh * DK + d)) * S_LEN + s0 + c8 * 8] = *(int4*)v;
    }
}

// ---------------------------------------------------------------------------
// bf16 MFMA GEMM: C[M,N] = A[M,K] @ Bt[N,K]^T + bias. 64x64 tile, BK=64.
// 256 thr = 4 waves (2x2), each wave 32x32 via 2x2 mfma_16x16x32 frags.
// ---------------------------------------------------------------------------
template <bool OUT_BF16>
__global__ __launch_bounds__(256) void gemm_bf(
    const short* __restrict__ A, const short* __restrict__ Bt,
    const float* __restrict__ bias, void* __restrict__ Cout,
    int M, int N, int K) {
    __shared__ __align__(16) short As[64][72];
    __shared__ __align__(16) short Bs[64][72];
    const int row0 = blockIdx.y * 64, col0 = blockIdx.x * 64;
    const int tid = threadIdx.x;
    const int w = tid >> 6, l = tid & 63, lm = l & 15, quad = l >> 4;
    const int wm = (w >> 1) * 32, wn = (w & 1) * 32;
    f32x4 acc[2][2] = {};

    for (int k0 = 0; k0 < K; k0 += 64) {
        __syncthreads();
#pragma unroll
        for (int i = 0; i < 2; ++i) {
            int idx = tid + i * 256;
            int r = idx >> 3, c8 = idx & 7;
            *(int4*)&As[r][c8 * 8] = *(const int4*)&A[(size_t)(row0 + r) * K + k0 + c8 * 8];
            *(int4*)&Bs[r][c8 * 8] = *(const int4*)&Bt[(size_t)(col0 + r) * K + k0 + c8 * 8];
        }
        __syncthreads();
#pragma unroll
        for (int kc = 0; kc < 2; ++kc) {
            bf16x8 a0 = *(const bf16x8*)&As[wm + lm][kc * 32 + quad * 8];
            bf16x8 a1 = *(const bf16x8*)&As[wm + 16 + lm][kc * 32 + quad * 8];
            bf16x8 b0 = *(const bf16x8*)&Bs[wn + lm][kc * 32 + quad * 8];
            bf16x8 b1 = *(const bf16x8*)&Bs[wn + 16 + lm][kc * 32 + quad * 8];
            acc[0][0] = mfma16(a0, b0, acc[0][0]);
            acc[0][1] = mfma16(a0, b1, acc[0][1]);
            acc[1][0] = mfma16(a1, b0, acc[1][0]);
            acc[1][1] = mfma16(a1, b1, acc[1][1]);
        }
    }
#pragma unroll
    for (int mi = 0; mi < 2; ++mi)
#pragma unroll
        for (int ni = 0; ni < 2; ++ni)
#pragma unroll
            for (int r = 0; r < 4; ++r) {
                int row = row0 + wm + mi * 16 + quad * 4 + r;
                int col = col0 + wn + ni * 16 + lm;
                float v = acc[mi][ni][r] + bias[col];
                if (OUT_BF16)
                    ((short*)Cout)[(size_t)row * N + col] = f2bf(v);
                else
                    ((float*)Cout)[(size_t)row * N + col] = v;
            }
}

// ---------------------------------------------------------------------------
// first nonpad token index per batch
// ---------------------------------------------------------------------------
__global__ __launch_bounds__(256) void fnp_scan(const int* __restrict__ tok,
                                                int* __restrict__ fnp) {
    __shared__ int mn;
    const int b = blockIdx.x;
    if (threadIdx.x == 0) mn = S_LEN;
    __syncthreads();
    int loc = S_LEN;
    for (int s = threadIdx.x; s < S_LEN; s += 256)
        if (tok[b * S_LEN + s] != 0) loc = min(loc, s);
    atomicMin(&mn, loc);
    __syncthreads();
    if (threadIdx.x == 0) fnp[b] = mn;
}

// ---------------------------------------------------------------------------
// Flash pass A: per (bh, 64-row q-tile), row max m and sumexp l over causal
// band k in [0, (qt+1)*64). Online softmax state per lane (4 rows each).
// ---------------------------------------------------------------------------
__global__ __launch_bounds__(256) void flash_ml(
    const short* __restrict__ Qb, const short* __restrict__ Kb,
    const int* __restrict__ tok, float* __restrict__ Mrow, float* __restrict__ Lrow) {
    const int bh = blockIdx.y, b = bh >> 4, h = bh & 15;
    const int qt = blockIdx.x, q0 = qt * 64;
    const int tid = threadIdx.x;
    const int w = tid >> 6, l = tid & 63, lm = l & 15, quad = l >> 4;
    __shared__ __align__(16) short Qs[64][72];
    __shared__ __align__(16) short Ks[64][72];
    __shared__ float padf[64];

#pragma unroll
    for (int i = 0; i < 2; ++i) {
        int idx = tid + i * 256;
        int r = idx >> 3, c8 = idx & 7;
        *(int4*)&Qs[r][c8 * 8] =
            *(const int4*)&Qb[((size_t)(b * S_LEN + q0 + r)) * DMODEL + h * DK + c8 * 8];
    }

    float mrun[4], lrun[4];
#pragma unroll
    for (int r = 0; r < 4; ++r) { mrun[r] = -INFINITY; lrun[r] = 0.f; }

    for (int kt = 0; kt <= qt; ++kt) {
        __syncthreads();
#pragma unroll
        for (int i = 0; i < 2; ++i) {
            int idx = tid + i * 256;
            int r = idx >> 3, c8 = idx & 7;
            *(int4*)&Ks[r][c8 * 8] =
                *(const int4*)&Kb[((size_t)(b * S_LEN + kt * 64 + r)) * DMODEL + h * DK + c8 * 8];
        }
        if (tid < 64) padf[tid] = (tok[b * S_LEN + kt * 64 + tid] == 0) ? 1.f : 0.f;
        __syncthreads();

        float sv[4][4];                    // [nt][r]
#pragma unroll
        for (int nt = 0; nt < 4; ++nt) {
            f32x4 acc = {0.f, 0.f, 0.f, 0.f};
#pragma unroll
            for (int kc = 0; kc < 2; ++kc) {
                bf16x8 a = *(const bf16x8*)&Qs[w * 16 + lm][kc * 32 + quad * 8];
                bf16x8 bb = *(const bf16x8*)&Ks[nt * 16 + lm][kc * 32 + quad * 8];
                acc = mfma16(a, bb, acc);
            }
            int kcol = kt * 64 + nt * 16 + lm;
            bool pad = padf[nt * 16 + lm] != 0.f;
#pragma unroll
            for (int r = 0; r < 4; ++r) {
                int qrow = q0 + w * 16 + quad * 4 + r;
                bool msk = pad || (kcol > qrow);
                sv[nt][r] = msk ? NEGV : acc[r] * 0.125f;
            }
        }
        float mx[4], ps[4];
#pragma unroll
        for (int r = 0; r < 4; ++r)
            mx[r] = fmaxf(fmaxf(sv[0][r], sv[1][r]), fmaxf(sv[2][r], sv[3][r]));
#pragma unroll
        for (int off = 1; off < 16; off <<= 1)
#pragma unroll
            for (int r = 0; r < 4; ++r) mx[r] = fmaxf(mx[r], __shfl_xor(mx[r], off));
#pragma unroll
        for (int r = 0; r < 4; ++r) {
            float mnew = fmaxf(mrun[r], mx[r]);
            float p = 0.f;
#pragma unroll
            for (int nt = 0; nt < 4; ++nt) p += __expf(sv[nt][r] - mnew);
            ps[r] = p;
            lrun[r] = lrun[r] * __expf(mrun[r] - mnew);
            mrun[r] = mnew;
        }
#pragma unroll
        for (int off = 1; off < 16; off <<= 1)
#pragma unroll
            for (int r = 0; r < 4; ++r) ps[r] += __shfl_xor(ps[r], off);
#pragma unroll
        for (int r = 0; r < 4; ++r) lrun[r] += ps[r];
    }

    if (lm == 0) {
#pragma unroll
        for (int r = 0; r < 4; ++r) {
            int qr = q0 + w * 16 + quad * 4 + r;
            Mrow[(size_t)bh * S_LEN + qr] = mrun[r];
            Lrow[(size_t)bh * S_LEN + qr] = lrun[r];
        }
    }
}

// ---------------------------------------------------------------------------
// Flash pass B: recompute scores, P = exp(s-m)/l, write fp32 attn (causal
// band), P -> LDS (bf16, A-frag layout) -> MFMA P@V -> ctx bf16.
// ---------------------------------------------------------------------------
__global__ __launch_bounds__(256) void flash_pb(
    const short* __restrict__ Qb, const short* __restrict__ Kb,
    const short* __restrict__ Vt, const int* __restrict__ tok,
    const float* __restrict__ Mrow, const float* __restrict__ Lrow,
    float* __restrict__ attn, short* __restrict__ ctxb) {
    const int bh = blockIdx.y, b = bh >> 4, h = bh & 15;
    const int qt = blockIdx.x, q0 = qt * 64;
    const int tid = threadIdx.x;
    const int w = tid >> 6, l = tid & 63, lm = l & 15, quad = l >> 4;
    __shared__ __align__(16) short Qs[64][72];
    __shared__ __align__(16) short Ks[64][72];
    __shared__ __align__(16) short Vs[64][72];
    __shared__ __align__(16) short Ps[64][72];
    __shared__ float padf[64];

#pragma unroll
    for (int i = 0; i < 2; ++i) {
        int idx = tid + i * 256;
        int r = idx >> 3, c8 = idx & 7;
        *(int4*)&Qs[r][c8 * 8] =
            *(const int4*)&Qb[((size_t)(b * S_LEN + q0 + r)) * DMODEL + h * DK + c8 * 8];
    }

    float mld[4], linv[4];
#pragma unroll
    for (int r = 0; r < 4; ++r) {
        int qr = q0 + w * 16 + quad * 4 + r;
        mld[r] = Mrow[(size_t)bh * S_LEN + qr];
        linv[r] = 1.f / Lrow[(size_t)bh * S_LEN + qr];
    }

    f32x4 oacc[4] = {};

    for (int kt = 0; kt <= qt; ++kt) {
        __syncthreads();
#pragma unroll
        for (int i = 0; i < 2; ++i) {
            int idx = tid + i * 256;
            int r = idx >> 3, c8 = idx & 7;
            *(int4*)&Ks[r][c8 * 8] =
                *(const int4*)&Kb[((size_t)(b * S_LEN + kt * 64 + r)) * DMODEL + h * DK + c8 * 8];
            *(int4*)&Vs[r][c8 * 8] =
                *(const int4*)&Vt[((size_t)(bh * DK + r)) * S_LEN + kt * 64 + c8 * 8];
        }
        if (tid < 64) padf[tid] = (tok[b * S_LEN + kt * 64 + tid] == 0) ? 1.f : 0.f;
        __syncthreads();

#pragma unroll
        for (int nt = 0; nt < 4; ++nt) {
            f32x4 acc = {0.f, 0.f, 0.f, 0.f};
#pragma unroll
            for (int kc = 0; kc < 2; ++kc) {
                bf16x8 a = *(const bf16x8*)&Qs[w * 16 + lm][kc * 32 + quad * 8];
                bf16x8 bb = *(const bf16x8*)&Ks[nt * 16 + lm][kc * 32 + quad * 8];
                acc = mfma16(a, bb, acc);
            }
            int kcol = kt * 64 + nt * 16 + lm;
            bool pad = padf[nt * 16 + lm] != 0.f;
#pragma unroll
            for (int r = 0; r < 4; ++r) {
                int qrow = q0 + w * 16 + quad * 4 + r;
                bool msk = pad || (kcol > qrow);
                float p = msk ? 0.f : __expf(acc[r] * 0.125f - mld[r]) * linv[r];
                attn[((size_t)bh * S_LEN + qrow) * S_LEN + kcol] = p;
                Ps[w * 16 + quad * 4 + r][nt * 16 + lm] = f2bf(p);
            }
        }
        // P (written by this wave's own lanes) -> A-frags; V -> B-frags
#pragma unroll
        for (int kc = 0; kc < 2; ++kc) {
            bf16x8 a = *(const bf16x8*)&Ps[w * 16 + lm][kc * 32 + quad * 8];
#pragma unroll
            for (int dt = 0; dt < 4; ++dt) {
                bf16x8 bv = *(const bf16x8*)&Vs[dt * 16 + lm][kc * 32 + quad * 8];
                oacc[dt] = mfma16(a, bv, oacc[dt]);
            }
        }
    }

#pragma unroll
    for (int dt = 0; dt < 4; ++dt)
#pragma unroll
        for (int r = 0; r < 4; ++r) {
            int qrow = q0 + w * 16 + quad * 4 + r;
            ctxb[((size_t)(b * S_LEN + qrow)) * DMODEL + h * DK + dt * 16 + lm] =
                f2bf(oacc[dt][r]);
        }
}

// ---------------------------------------------------------------------------
// Zero the strict-upper (causal-masked) tiles of attn.
// ---------------------------------------------------------------------------
__global__ __launch_bounds__(256) void fill_upper(float* __restrict__ attn) {
    const int qt = blockIdx.x, bh = blockIdx.y;
    const int ce = (qt + 1) * 64;
    const int n = S_LEN - ce;
    if (n <= 0) return;
    const int n4 = n >> 2;
    float4 z = {0.f, 0.f, 0.f, 0.f};
    float* base = attn + ((size_t)bh * S_LEN + qt * 64) * S_LEN;
    for (int i = threadIdx.x; i < 64 * n4; i += 256) {
        int row = i / n4, c = i % n4;
        *(float4*)&base[(size_t)row * S_LEN + ce + c * 4] = z;
    }
}

// ---------------------------------------------------------------------------
// Fully-masked rows (q < first-nonpad): attn row = 1/2048 (all heads),
// ctx row = mean(V). Rare/usually-empty; blocks early-out.
// ---------------------------------------------------------------------------
__global__ __launch_bounds__(256) void fix_fullmask(
    const int* __restrict__ fnp, const short* __restrict__ Vb,
    float* __restrict__ attn, short* __restrict__ ctxb) {
    const int b = blockIdx.x >> 11, q = blockIdx.x & 2047;
    if (q >= fnp[b]) return;
    const float u = 1.f / (float)S_LEN;
    float4 uu = {u, u, u, u};
    for (int i = threadIdx.x; i < NH * (S_LEN / 4); i += 256) {
        int h = i / (S_LEN / 4), c4 = i % (S_LEN / 4);
        *(float4*)&attn[(((size_t)(b * NH + h) * S_LEN + q)) * S_LEN + c4 * 4] = uu;
    }
    for (int d = threadIdx.x; d < DMODEL; d += 256) {
        float sv = 0.f;
        for (int s = 0; s < S_LEN; ++s)
            sv += bf2f(Vb[((size_t)(b * S_LEN + s)) * DMODEL + d]);
        ctxb[((size_t)(b * S_LEN + q)) * DMODEL + d] = f2bf(sv * u);
    }
}

extern "C" void kernel_launch(void* const* d_in, const int* in_sizes, int n_in,
                              void* d_out, int out_size, void* d_ws, size_t ws_size,
                              hipStream_t stream) {
    const float* x  = (const float*)d_in[0];
    const int*  tok = (const int*)d_in[1];
    const float* wq = (const float*)d_in[2];
    const float* bq = (const float*)d_in[3];
    const float* wk = (const float*)d_in[4];
    const float* bk = (const float*)d_in[5];
    const float* wv = (const float*)d_in[6];
    const float* bv = (const float*)d_in[7];
    const float* wo = (const float*)d_in[8];
    const float* bo = (const float*)d_in[9];

    float* out  = (float*)d_out;
    float* attn = out + (size_t)B_SZ * S_LEN * DMODEL;

    const size_t NTOK = (size_t)B_SZ * S_LEN;        // 4096
    const size_t NE   = NTOK * DMODEL;               // 4,194,304
    short* xb   = (short*)d_ws;
    short* Wt   = xb + NE;                           // 4 x 1024x1024
    short* Qb   = Wt + 4 * (size_t)DMODEL * DMODEL;
    short* Kb   = Qb + NE;
    short* Vb   = Kb + NE;
    short* Vt   = Vb + NE;
    short* ctxb = Vt + NE;
    float* Mrow = (float*)(ctxb + NE);
    float* Lrow = Mrow + (size_t)B_SZ * NH * S_LEN;
    int*   fnp  = (int*)(Lrow + (size_t)B_SZ * NH * S_LEN);

    dim3 blk(256);

    cvt_bf16<<<dim3((int)(NE / 4 / 256)), blk, 0, stream>>>(x, xb, (int)(NE / 4));
    wtrans<<<dim3(16, 16), blk, 0, stream>>>(wq, Wt + 0 * (size_t)DMODEL * DMODEL);
    wtrans<<<dim3(16, 16), blk, 0, stream>>>(wk, Wt + 1 * (size_t)DMODEL * DMODEL);
    wtrans<<<dim3(16, 16), blk, 0, stream>>>(wv, Wt + 2 * (size_t)DMODEL * DMODEL);
    wtrans<<<dim3(16, 16), blk, 0, stream>>>(wo, Wt + 3 * (size_t)DMODEL * DMODEL);

    dim3 g_gemm(DMODEL / 64, (int)(NTOK / 64));      // (16, 64)
    gemm_bf<true><<<g_gemm, blk, 0, stream>>>(xb, Wt + 0 * (size_t)DMODEL * DMODEL, bq, Qb,
                                              (int)NTOK, DMODEL, DMODEL);
    gemm_bf<true><<<g_gemm, blk, 0, stream>>>(xb, Wt + 1 * (size_t)DMODEL * DMODEL, bk, Kb,
                                              (int)NTOK, DMODEL, DMODEL);
    gemm_bf<true><<<g_gemm, blk, 0, stream>>>(xb, Wt + 2 * (size_t)DMODEL * DMODEL, bv, Vb,
                                              (int)NTOK, DMODEL, DMODEL);

    vtrans<<<dim3(S_LEN / 64, B_SZ * NH), blk, 0, stream>>>(Vb, Vt);
    fnp_scan<<<dim3(B_SZ), blk, 0, stream>>>(tok, fnp);

    flash_ml<<<dim3(S_LEN / 64, B_SZ * NH), blk, 0, stream>>>(Qb, Kb, tok, Mrow, Lrow);
    flash_pb<<<dim3(S_LEN / 64, B_SZ * NH), blk, 0, stream>>>(Qb, Kb, Vt, tok, Mrow, Lrow,
                                                              attn, ctxb);
    fill_upper<<<dim3(S_LEN / 64, B_SZ * NH), blk, 0, stream>>>(attn);
    fix_fullmask<<<dim3(B_SZ * S_LEN), blk, 0, stream>>>(fnp, Vb, attn, ctxb);

    gemm_bf<false><<<g_gemm, blk, 0, stream>>>(ctxb, Wt + 3 * (size_t)DMODEL * DMODEL, bo, out,
                                               (int)NTOK, DMODEL, DMODEL);
}